// Round 16
// baseline (159.884 us; speedup 1.0000x reference)
//
#include <hip/hip_runtime.h>
#include <math.h>

#define BTOT   32768
#define LAT    128
#define H      17
#define TSTEPS 50
#define ROWS   64       // rows per block = lanes per wave
#define TPB    256      // 4 waves: wave g owns gate g
#define OSTR   (TSTEPS * H)   // 850

#define LOG2E 1.4426950408889634f

// smem union: phase-1 x_tile overlays the T-loop exchange buffers.
// abuf row stride 84 words (84 mod 32 = 20 -> lane-bank residues
// {0,20,8,28,16,4,24,12}: full spread for b128). gate-block stride 20 (16B-aligned).
// hbuf row stride 20 (same full-spread property).
#define ABSTR  84
#define HBSTR  20

__device__ __forceinline__ float exp2g(float x) {
    float r; asm("v_exp_f32 %0, %1" : "=v"(r) : "v"(x)); return r;
}
// sigmoid(x) = rcp(1 + exp2(-x*log2e)); tanh(x) = 1 - 2*rcp(exp2(2x*log2e)+1).
// Saturation-safe (inf -> rcp 0). f32 only (R9: recurrence amplifies error ~1e3x).
__device__ __forceinline__ float fsig(float x) {
    return __builtin_amdgcn_rcpf(1.0f + exp2g(x * (-LOG2E)));
}
__device__ __forceinline__ float ftanh(float x) {
    return fmaf(-2.0f, __builtin_amdgcn_rcpf(exp2g(x * (2.0f * LOG2E)) + 1.0f), 1.0f);
}

__global__ __launch_bounds__(TPB, 2)
void lstm_gs(const float* __restrict__ x,
             const float* __restrict__ W_h0, const float* __restrict__ b_h0,
             const float* __restrict__ W_c0, const float* __restrict__ b_c0,
             const float* __restrict__ W_ih, const float* __restrict__ W_hh,
             const float* __restrict__ b_ih, const float* __restrict__ b_hh,
             float* __restrict__ out)
{
    __shared__ __align__(16) float smem[ROWS * 132];          // 33.8 KB
    float (*xt)[132]   = (float(*)[132])smem;                 // phase 1
    float (*ab)[ABSTR] = (float(*)[ABSTR])smem;               // acts: [r][g*20+e]
    float (*hb)[HBSTR] = (float(*)[HBSTR])(smem + ROWS * ABSTR); // h: [r][e]

    const int t = threadIdx.x;
    // g MUST be wave-uniform for the compiler's scalarizer: W addresses become
    // s_load + SGPR operands on v_fmac (the whole point of this decomposition).
    const int g_u = __builtin_amdgcn_readfirstlane(t >> 6);   // gate 0..3
    const int r   = t & 63;                                   // row lane
    const int grow = blockIdx.x * ROWS + r;                   // exact fit, no masks
    const int e0  = g_u * 4;                                  // tail partition base
    const int nep = (g_u == 3) ? 5 : 4;                       // w3 owns e 12..16

    // ---- stage x tile ----
    for (int i = t; i < ROWS * 32; i += TPB) {
        int rr = i >> 5, c4 = (i & 31) * 4;
        *(float4*)&xt[rr][c4] = *(const float4*)(x + (size_t)(blockIdx.x * ROWS + rr) * LAT + c4);
    }
    __syncthreads();

    // ---- phase 1: xg[17] (this gate, this row) + h0/c0 for the partition ----
    float xg[H], h0a[5], c0a[5];
#pragma unroll
    for (int e = 0; e < H; ++e) xg[e] = 0.0f;
#pragma unroll
    for (int p = 0; p < 5; ++p) { h0a[p] = 0.0f; c0a[p] = 0.0f; }

    const float* Wih_g = W_ih + (size_t)g_u * H * LAT;        // uniform
    for (int kb = 0; kb < 32; ++kb) {
        float4 xv = *(const float4*)&xt[r][kb * 4];
#pragma unroll
        for (int e = 0; e < H; ++e) {
            const float* wr = Wih_g + e * LAT + kb * 4;       // uniform -> s_load
            xg[e] = fmaf(xv.x, wr[0], xg[e]);
            xg[e] = fmaf(xv.y, wr[1], xg[e]);
            xg[e] = fmaf(xv.z, wr[2], xg[e]);
            xg[e] = fmaf(xv.w, wr[3], xg[e]);
        }
#pragma unroll
        for (int p = 0; p < 5; ++p) {
            if (p < nep) {
                const float* wh = W_h0 + (e0 + p) * LAT + kb * 4;   // uniform
                const float* wc = W_c0 + (e0 + p) * LAT + kb * 4;
                h0a[p] = fmaf(xv.x, wh[0], h0a[p]);
                h0a[p] = fmaf(xv.y, wh[1], h0a[p]);
                h0a[p] = fmaf(xv.z, wh[2], h0a[p]);
                h0a[p] = fmaf(xv.w, wh[3], h0a[p]);
                c0a[p] = fmaf(xv.x, wc[0], c0a[p]);
                c0a[p] = fmaf(xv.y, wc[1], c0a[p]);
                c0a[p] = fmaf(xv.z, wc[2], c0a[p]);
                c0a[p] = fmaf(xv.w, wc[3], c0a[p]);
            }
        }
    }
#pragma unroll
    for (int e = 0; e < H; ++e) xg[e] += b_ih[g_u * H + e] + b_hh[g_u * H + e];

    float c[5];
#pragma unroll
    for (int p = 0; p < 5; ++p) {
        if (p < nep) { h0a[p] += b_h0[e0 + p]; c[p] = c0a[p] + b_c0[e0 + p]; }
        else c[p] = 0.0f;
    }

    // ---- publish h0 (x_tile reads are done; smem is re-purposed) ----
    __syncthreads();
#pragma unroll
    for (int p = 0; p < 5; ++p) if (p < nep) hb[r][e0 + p] = h0a[p];
    __syncthreads();

    float h_[H];
    {
        float4 H0 = *(const float4*)&hb[r][0];
        float4 H1 = *(const float4*)&hb[r][4];
        float4 H2 = *(const float4*)&hb[r][8];
        float4 H3 = *(const float4*)&hb[r][12];
        h_[0]=H0.x; h_[1]=H0.y; h_[2]=H0.z;  h_[3]=H0.w;
        h_[4]=H1.x; h_[5]=H1.y; h_[6]=H1.z;  h_[7]=H1.w;
        h_[8]=H2.x; h_[9]=H2.y; h_[10]=H2.z; h_[11]=H2.w;
        h_[12]=H3.x; h_[13]=H3.y; h_[14]=H3.z; h_[15]=H3.w;
        h_[16]=hb[r][16];
    }

    const float* Wg = W_hh + g_u * H * H;                     // uniform base
    float* orow = out + (size_t)grow * OSTR;

    // ---- T-loop: dots (SGPR W) -> own-gate act -> exchange -> partition tail ----
#pragma unroll 1
    for (int tt = 0; tt < TSTEPS; ++tt) {
        // 17 independent 17-deep dots; W from SGPRs, h from VGPRs. No LDS here.
        float a[H];
#pragma unroll
        for (int e = 0; e < H; ++e) {
            float acc = xg[e];
            const float* wr = Wg + e * H;                     // uniform -> s_load
#pragma unroll
            for (int k = 0; k < H; ++k) acc = fmaf(wr[k], h_[k], acc);
            a[e] = acc;
        }
        // own-gate activation (wave-uniform branch)
        if (g_u == 2) {
#pragma unroll
            for (int e = 0; e < H; ++e) a[e] = ftanh(a[e]);
        } else {
#pragma unroll
            for (int e = 0; e < H; ++e) a[e] = fsig(a[e]);
        }
        // write acts to [r][g*20 + e]: 4x b128 + b32, aligned, full bank spread
        {
            const int gb = g_u * 20;
            *(float4*)&ab[r][gb + 0]  = make_float4(a[0],  a[1],  a[2],  a[3]);
            *(float4*)&ab[r][gb + 4]  = make_float4(a[4],  a[5],  a[6],  a[7]);
            *(float4*)&ab[r][gb + 8]  = make_float4(a[8],  a[9],  a[10], a[11]);
            *(float4*)&ab[r][gb + 12] = make_float4(a[12], a[13], a[14], a[15]);
            ab[r][gb + 16] = a[16];
        }
        __syncthreads();   // acts published (also h-read WAR: all reads long done)

        // partition tail: wave w updates c,h for e in [e0, e0+nep)
        {
            float4 qi = *(const float4*)&ab[r][ 0 + e0];
            float4 qf = *(const float4*)&ab[r][20 + e0];
            float4 qg = *(const float4*)&ab[r][40 + e0];
            float4 qo = *(const float4*)&ab[r][60 + e0];
            float* ot = orow + tt * H;

            c[0] = fmaf(qf.x, c[0], qi.x * qg.x);
            { float hv = qo.x * ftanh(c[0]); hb[r][e0 + 0] = hv; ot[e0 + 0] = hv; }
            c[1] = fmaf(qf.y, c[1], qi.y * qg.y);
            { float hv = qo.y * ftanh(c[1]); hb[r][e0 + 1] = hv; ot[e0 + 1] = hv; }
            c[2] = fmaf(qf.z, c[2], qi.z * qg.z);
            { float hv = qo.z * ftanh(c[2]); hb[r][e0 + 2] = hv; ot[e0 + 2] = hv; }
            c[3] = fmaf(qf.w, c[3], qi.w * qg.w);
            { float hv = qo.w * ftanh(c[3]); hb[r][e0 + 3] = hv; ot[e0 + 3] = hv; }
            if (nep == 5) {
                float si = ab[r][16], sf = ab[r][36], sg = ab[r][56], so = ab[r][76];
                c[4] = fmaf(sf, c[4], si * sg);
                float hv = so * ftanh(c[4]); hb[r][16] = hv; ot[16] = hv;
            }
        }
        __syncthreads();   // h published (also abuf WAR for next iter)

        // reload full h
        {
            float4 H0 = *(const float4*)&hb[r][0];
            float4 H1 = *(const float4*)&hb[r][4];
            float4 H2 = *(const float4*)&hb[r][8];
            float4 H3 = *(const float4*)&hb[r][12];
            h_[0]=H0.x; h_[1]=H0.y; h_[2]=H0.z;  h_[3]=H0.w;
            h_[4]=H1.x; h_[5]=H1.y; h_[6]=H1.z;  h_[7]=H1.w;
            h_[8]=H2.x; h_[9]=H2.y; h_[10]=H2.z; h_[11]=H2.w;
            h_[12]=H3.x; h_[13]=H3.y; h_[14]=H3.z; h_[15]=H3.w;
            h_[16]=hb[r][16];
        }
    }
}

extern "C" void kernel_launch(void* const* d_in, const int* in_sizes, int n_in,
                              void* d_out, int out_size, void* d_ws, size_t ws_size,
                              hipStream_t stream)
{
    const float* x    = (const float*)d_in[0];
    const float* W_h0 = (const float*)d_in[1];
    const float* b_h0 = (const float*)d_in[2];
    const float* W_c0 = (const float*)d_in[3];
    const float* b_c0 = (const float*)d_in[4];
    const float* W_ih = (const float*)d_in[5];
    const float* W_hh = (const float*)d_in[6];
    const float* b_ih = (const float*)d_in[7];
    const float* b_hh = (const float*)d_in[8];
    float* out = (float*)d_out;

    (void)d_ws; (void)ws_size;  // no workspace used

    hipLaunchKernelGGL(lstm_gs, dim3(BTOT / ROWS), dim3(TPB), 0, stream,
                       x, W_h0, b_h0, W_c0, b_c0, W_ih, W_hh, b_ih, b_hh, out);
}

// Round 17
// 141.760 us; speedup vs baseline: 1.1279x; 1.1279x over previous
//
#include <hip/hip_runtime.h>
#include <math.h>

#define BTOT   32768
#define LAT    128
#define H      17
#define G4     68      // 4*H
#define TSTEPS 50
#define NPR    102     // projection rows: 68 (W_ih) + 17 (W_h0) + 17 (W_c0)
#define WPAD   40      // Wbuf row stride (k-quarter staging, R14-proven)
#define XPAD   132

#define NW     8              // waves per block
#define RPB    48             // 6 rows per wave: set A rows rl, set B rows rl+3
#define TPB    512

#define LOG2E 1.4426950408889634f

// x_tile stride 132: rows r,r+8 alias -> 2-bit XOR key (R14: part of 2.98M result).
#define XSWZ(r, c4)   ((c4) ^ ((((r) >> 3) & 3) << 2))
// Wbuf stride 40: rows r,r+4 alias -> key on bits 2-3 (R14-proven).
#define WSWZ(row, c4) ((c4) ^ ((((row) >> 2) & 3) << 2))

// v_exp_f32 IS exp2 -- gates pre-scaled by -log2e (i,f,o) / +2log2e (g), so the
// tail is exp2+rcp only (R14-proven math, absmax 0.0039).
__device__ __forceinline__ float exp2g(float x) {
    float r; asm("v_exp_f32 %0, %1" : "=v"(r) : "v"(x)); return r;
}
#define FMAC(acc, w, h) asm("v_fmac_f32 %0, %1, %2" : "+v"(acc) : "v"(w), "v"(h))

#define FQ(Q, HV) \
    FMAC(ai,Wi[4*Q+0],HV.x); FMAC(af,Wf[4*Q+0],HV.x); FMAC(ag,Wg[4*Q+0],HV.x); FMAC(ao,Wo[4*Q+0],HV.x); \
    FMAC(ai,Wi[4*Q+1],HV.y); FMAC(af,Wf[4*Q+1],HV.y); FMAC(ag,Wg[4*Q+1],HV.y); FMAC(ao,Wo[4*Q+1],HV.y); \
    FMAC(ai,Wi[4*Q+2],HV.z); FMAC(af,Wf[4*Q+2],HV.z); FMAC(ag,Wg[4*Q+2],HV.z); FMAC(ao,Wo[4*Q+2],HV.z); \
    FMAC(ai,Wi[4*Q+3],HV.w); FMAC(af,Wf[4*Q+3],HV.w); FMAC(ag,Wg[4*Q+3],HV.w); FMAC(ao,Wo[4*Q+3],HV.w);

__global__ __launch_bounds__(TPB, 2)
void lstm_fused(const float* __restrict__ x,
                const float* __restrict__ W_h0, const float* __restrict__ b_h0,
                const float* __restrict__ W_c0, const float* __restrict__ b_c0,
                const float* __restrict__ W_ih, const float* __restrict__ W_hh,
                const float* __restrict__ b_ih, const float* __restrict__ b_hh,
                float* __restrict__ out)
{
    __shared__ __align__(16) float x_tile[RPB][XPAD];   // 25.3 KB
    __shared__ __align__(16) float Wbuf[NPR][WPAD];     // 16.3 KB (one k-quarter)
    __shared__ __align__(16) float Wl[G4 * H];          //  4.6 KB (W_hh f32)
    __shared__ __align__(16) float hbuf[NW][7][20];     //  4.5 KB (6 rows + dummy row 6)

    const int t    = threadIdx.x;
    const int w    = t >> 6;
    const int lane = t & 63;
    const bool active = lane < 3 * H;         // 51
    const int rl = active ? (lane / H) : 0;   // 0..2
    const int j  = active ? (lane % H) : 0;   // 0..16
    const int r0 = w * 6 + rl;                // set-A local row; set B = r0+3
    const int grow0 = blockIdx.x * RPB;

    int gA = grow0 + r0,     gB = grow0 + r0 + 3;
    const bool vA = active && (gA < BTOT), vB = active && (gB < BTOT);
    if (gA >= BTOT) gA = BTOT - 1;
    if (gB >= BTOT) gB = BTOT - 1;

    // ---- stage x tile (rows clamped) + W_hh; all 512 threads ----
    for (int i = t; i < RPB * 32; i += TPB) {
        int rr = i >> 5, c4 = (i & 31) * 4;
        int gr = grow0 + rr; if (gr >= BTOT) gr = BTOT - 1;
        *(float4*)&x_tile[rr][XSWZ(rr, c4)] = *(const float4*)(x + (size_t)gr * LAT + c4);
    }
    for (int i = t; i < G4 * H; i += TPB) Wl[i] = W_hh[i];

    // ---- phase 1: projections for both sets, four k-quarters of 32 ----
    float acc[12];
#pragma unroll
    for (int s = 0; s < 12; ++s) acc[s] = 0.0f;
    const int rows6[6] = { j, 17 + j, 34 + j, 51 + j, 68 + j, 85 + j };
    for (int qh = 0; qh < 4; ++qh) {
        __syncthreads();  // qh=0: x_tile/Wl ready; else WAR on Wbuf
        for (int i = t; i < NPR * 8; i += TPB) {
            int row = i >> 3, c4 = (i & 7) * 4;
            const float* src = (row < G4) ? (W_ih + row * LAT)
                             : (row < 85) ? (W_h0 + (row - G4) * LAT)
                                          : (W_c0 + (row - 85) * LAT);
            *(float4*)&Wbuf[row][WSWZ(row, c4)] = *(const float4*)(src + qh * 32 + c4);
        }
        __syncthreads();
        for (int kb = 0; kb < 8; ++kb) {
            const int xc = qh * 32 + kb * 4;
            float4 xa = *(const float4*)&x_tile[r0][XSWZ(r0, xc)];
            float4 xb = *(const float4*)&x_tile[r0 + 3][XSWZ(r0 + 3, xc)];
#pragma unroll
            for (int p = 0; p < 6; ++p) {
                const int row = rows6[p];
                float4 wv = *(const float4*)&Wbuf[row][WSWZ(row, kb * 4)];
                acc[p]     = fmaf(xa.x, wv.x, acc[p]);
                acc[p]     = fmaf(xa.y, wv.y, acc[p]);
                acc[p]     = fmaf(xa.z, wv.z, acc[p]);
                acc[p]     = fmaf(xa.w, wv.w, acc[p]);
                acc[6 + p] = fmaf(xb.x, wv.x, acc[6 + p]);
                acc[6 + p] = fmaf(xb.y, wv.y, acc[6 + p]);
                acc[6 + p] = fmaf(xb.z, wv.z, acc[6 + p]);
                acc[6 + p] = fmaf(xb.w, wv.w, acc[6 + p]);
            }
        }
    }

    // ---- biases + exp2 pre-scaling (i,f,o: -log2e; g: +2log2e) ----
    const float bi0 = b_ih[j]      + b_hh[j];
    const float bi1 = b_ih[17 + j] + b_hh[17 + j];
    const float bi2 = b_ih[34 + j] + b_hh[34 + j];
    const float bi3 = b_ih[51 + j] + b_hh[51 + j];
    float xgi[2], xgf[2], xgg[2], xgo[2], hS[2], cS[2];
#pragma unroll
    for (int s = 0; s < 2; ++s) {
        xgi[s] = (acc[s * 6 + 0] + bi0) * (-LOG2E);
        xgf[s] = (acc[s * 6 + 1] + bi1) * (-LOG2E);
        xgg[s] = (acc[s * 6 + 2] + bi2) * (2.0f * LOG2E);
        xgo[s] = (acc[s * 6 + 3] + bi3) * (-LOG2E);
        hS[s]  =  acc[s * 6 + 4] + b_h0[j];
        cS[s]  =  acc[s * 6 + 5] + b_c0[j];
    }

    // ---- W_hh rows -> registers, pre-scaled per gate ----
    float Wi[H], Wf[H], Wg[H], Wo[H];
#pragma unroll
    for (int k = 0; k < H; ++k) {
        Wi[k] = Wl[(0 * H + j) * H + k] * (-LOG2E);
        Wf[k] = Wl[(1 * H + j) * H + k] * (-LOG2E);
        Wg[k] = Wl[(2 * H + j) * H + k] * (2.0f * LOG2E);
        Wo[k] = Wl[(3 * H + j) * H + k] * (-LOG2E);
        asm volatile("" : "+v"(Wi[k]), "+v"(Wf[k]), "+v"(Wg[k]), "+v"(Wo[k]));
    }

    // ---- phase 2: R13 depth-2 A/B pipeline, zero barriers ----
    // Predication-free hbuf writes: inactive lanes target dummy row 6.
    float* hwA = active ? &hbuf[w][rl][j]     : &hbuf[w][6][lane - 51];
    float* hwB = active ? &hbuf[w][3 + rl][j] : &hbuf[w][6][lane - 51];
    const float* hbA = &hbuf[w][rl][0];
    const float* hbB = &hbuf[w][3 + rl][0];
    float* orowA = out + (size_t)gA * (TSTEPS * H) + j;
    float* orowB = out + (size_t)gB * (TSTEPS * H) + j;

    // prologue: A's step-0 exchange
    *hwA = hS[0];
    float4 a0 = *(const float4*)&hbA[0];
    float4 a1 = *(const float4*)&hbA[4];
    float4 a2 = *(const float4*)&hbA[8];
    float4 a3 = *(const float4*)&hbA[12];
    float  a4 = hbA[16];

    for (int tt = 0; tt < TSTEPS; ++tt) {
        // --- B exchange for this step (consumed after A's compute) ---
        *hwB = hS[1];
        float4 b0 = *(const float4*)&hbB[0];
        float4 b1 = *(const float4*)&hbB[4];
        float4 b2 = *(const float4*)&hbB[8];
        float4 b3 = *(const float4*)&hbB[12];
        float  b4 = hbB[16];

        // --- A compute ---
        {
            float ai = xgi[0], af = xgf[0], ag = xgg[0], ao = xgo[0];
            FQ(0, a0) FQ(1, a1) FQ(2, a2) FQ(3, a3)
            FMAC(ai, Wi[16], a4); FMAC(af, Wf[16], a4);
            FMAC(ag, Wg[16], a4); FMAC(ao, Wo[16], a4);
            const float ig = __builtin_amdgcn_rcpf(1.0f + exp2g(ai));
            const float fg = __builtin_amdgcn_rcpf(1.0f + exp2g(af));
            const float og = __builtin_amdgcn_rcpf(1.0f + exp2g(ao));
            const float tg = __builtin_amdgcn_rcpf(exp2g(ag) + 1.0f);
            cS[0] = fmaf(fg, cS[0], ig * fmaf(-2.0f, tg, 1.0f));
            const float tc = __builtin_amdgcn_rcpf(exp2g(cS[0] * (2.0f * LOG2E)) + 1.0f);
            hS[0] = og * fmaf(-2.0f, tc, 1.0f);
        }

        // --- A exchange for NEXT step (hidden under B's compute) ---
        *hwA = hS[0];
        a0 = *(const float4*)&hbA[0];
        a1 = *(const float4*)&hbA[4];
        a2 = *(const float4*)&hbA[8];
        a3 = *(const float4*)&hbA[12];
        a4 = hbA[16];

        // --- B compute ---
        {
            float ai = xgi[1], af = xgf[1], ag = xgg[1], ao = xgo[1];
            FQ(0, b0) FQ(1, b1) FQ(2, b2) FQ(3, b3)
            FMAC(ai, Wi[16], b4); FMAC(af, Wf[16], b4);
            FMAC(ag, Wg[16], b4); FMAC(ao, Wo[16], b4);
            const float ig = __builtin_amdgcn_rcpf(1.0f + exp2g(ai));
            const float fg = __builtin_amdgcn_rcpf(1.0f + exp2g(af));
            const float og = __builtin_amdgcn_rcpf(1.0f + exp2g(ao));
            const float tg = __builtin_amdgcn_rcpf(exp2g(ag) + 1.0f);
            cS[1] = fmaf(fg, cS[1], ig * fmaf(-2.0f, tg, 1.0f));
            const float tc = __builtin_amdgcn_rcpf(exp2g(cS[1] * (2.0f * LOG2E)) + 1.0f);
            hS[1] = og * fmaf(-2.0f, tc, 1.0f);
        }

        // --- stores (async vmem, off the critical path) ---
        if (vA) orowA[0] = hS[0];
        if (vB) orowB[0] = hS[1];
        orowA += H; orowB += H;
    }
}

extern "C" void kernel_launch(void* const* d_in, const int* in_sizes, int n_in,
                              void* d_out, int out_size, void* d_ws, size_t ws_size,
                              hipStream_t stream)
{
    const float* x    = (const float*)d_in[0];
    const float* W_h0 = (const float*)d_in[1];
    const float* b_h0 = (const float*)d_in[2];
    const float* W_c0 = (const float*)d_in[3];
    const float* b_c0 = (const float*)d_in[4];
    const float* W_ih = (const float*)d_in[5];
    const float* W_hh = (const float*)d_in[6];
    const float* b_ih = (const float*)d_in[7];
    const float* b_hh = (const float*)d_in[8];
    float* out = (float*)d_out;

    (void)d_ws; (void)ws_size;  // no workspace used

    const int nblk = (BTOT + RPB - 1) / RPB;   // 683
    hipLaunchKernelGGL(lstm_fused, dim3(nblk), dim3(TPB), 0, stream,
                       x, W_h0, b_h0, W_c0, b_c0, W_ih, W_hh, b_ih, b_hh, out);
}

// Round 18
// 135.039 us; speedup vs baseline: 1.1840x; 1.0498x over previous
//
#include <hip/hip_runtime.h>
#include <math.h>

#define BTOT   32768
#define LAT    128
#define H      17
#define G4     68      // 4*H
#define TSTEPS 50
#define NPR    102     // projection rows: 68 (W_ih) + 17 (W_h0) + 17 (W_c0)
#define WPAD   72

#define NW     8              // waves per block
#define RPB    48             // 6 rows per wave (3 in set A, 3 in set B)
#define TPB    512

typedef float float2v __attribute__((ext_vector_type(2)));

// x_tile stride 132: rows r,r+8,r+16 alias -> 2-bit XOR key (R13-proven).
#define XSWZ(r, c4)   ((c4) ^ ((((r) >> 3) & 3) << 2))
// Wbuf stride 72: rows j,j+4,j+8,j+12 alias -> key on bits 2-3 (R13-proven).
#define WSWZ(row, c4) ((c4) ^ ((((row) >> 2) & 3) << 2))

// f32-only gates (R9: recurrence amplifies per-step error ~1e3x; f16 fails).
__device__ __forceinline__ float fsigmoid(float x) {
    float e = __expf(-x);
    return __builtin_amdgcn_rcpf(1.0f + e);
}
// tanh(x) = 1 - 2*rcp(exp(2x)+1); +inf -> 1, -inf -> -1, no divide.
__device__ __forceinline__ float ftanhf(float x) {
    float e = __expf(2.0f * x);
    float t = __builtin_amdgcn_rcpf(e + 1.0f);
    return fmaf(-2.0f, t, 1.0f);
}

// Packed f32 FMA: one instr = 2 FMAs on VGPR pairs. Halves dot instruction
// count (68->36) and chain depth (17->9). Exact f32 math.
#define PKFMA(acc, w, hh) \
    asm("v_pk_fma_f32 %0, %1, %2, %0" : "+v"(acc) : "v"(w), "v"(hh))

// (512,2): reg cap 256 -> structurally no spill (R11/R12 lesson).
__global__ __launch_bounds__(TPB, 2)
void lstm_fused(const float* __restrict__ x,
                const float* __restrict__ W_h0, const float* __restrict__ b_h0,
                const float* __restrict__ W_c0, const float* __restrict__ b_c0,
                const float* __restrict__ W_ih, const float* __restrict__ W_hh,
                const float* __restrict__ b_ih, const float* __restrict__ b_hh,
                float* __restrict__ out)
{
    __shared__ float x_tile[RPB][132];      // 25.3 KB (XOR-swizzled cols)
    __shared__ float Wbuf[NPR][WPAD];       // 29.4 KB (one k-half, XOR-swizzled)
    __shared__ float Wl[G4 * H];            //  4.6 KB (W_hh f32)
    __shared__ float hbuf[NW][6][20];       //  3.8 KB (6 wave-private h rows)
    // total 63.1 KB -> 2 blocks/CU by LDS (same as R13)

    const int t    = threadIdx.x;
    const int w    = t >> 6;
    const int lane = t & 63;
    const bool active = lane < 3 * H;         // 51
    const int rl = active ? (lane / H) : 0;   // 0..2
    const int j  = active ? (lane % H) : 0;   // 0..16
    const int rA = w * 6 + rl;                // set-A row (0..47 local)
    const int rB = rA + 3;                    // set-B row
    const int grow0 = blockIdx.x * RPB;
    int growA = grow0 + rA;
    int growB = grow0 + rB;
    const bool validA = active && (growA < BTOT);
    const bool validB = active && (growB < BTOT);
    if (growA >= BTOT) growA = BTOT - 1;
    if (growB >= BTOT) growB = BTOT - 1;

    // ---- stage x tile (rows clamped) + W_hh; all 512 threads ----
    for (int i = t; i < RPB * 32; i += TPB) {              // 32 float4 per row
        int rr = i >> 5, c4 = (i & 31) * 4;
        int gr = grow0 + rr; if (gr >= BTOT) gr = BTOT - 1;
        *(float4*)&x_tile[rr][XSWZ(rr, c4)] =
            *(const float4*)(x + (size_t)gr * LAT + c4);
    }
    for (int i = t; i < G4 * H; i += TPB) Wl[i] = W_hh[i];

    // ---- phase 1: projections for BOTH row-sets, two k-halves of 64 ----
    float acc[12];                                         // A: 0-5, B: 6-11
#pragma unroll
    for (int s = 0; s < 12; ++s) acc[s] = 0.0f;
    const int rows6[6] = { j, 17 + j, 34 + j, 51 + j, 68 + j, 85 + j };
    for (int kh = 0; kh < 2; ++kh) {
        __syncthreads();  // kh=0: x_tile/Wl ready; kh=1: WAR on Wbuf
        for (int i = t; i < NPR * 16; i += TPB) {          // 16 float4 per half-row
            int row = i >> 4, c4 = (i & 15) * 4;
            const float* src = (row < G4) ? (W_ih + row * LAT)
                             : (row < 85) ? (W_h0 + (row - G4) * LAT)
                                          : (W_c0 + (row - 85) * LAT);
            *(float4*)&Wbuf[row][WSWZ(row, c4)] = *(const float4*)(src + kh * 64 + c4);
        }
        __syncthreads();  // half ready

        for (int kb = 0; kb < 16; ++kb) {
            const int xc = kh * 64 + kb * 4;
            float4 xa = *(const float4*)&x_tile[rA][XSWZ(rA, xc)];
            float4 xb = *(const float4*)&x_tile[rB][XSWZ(rB, xc)];
#pragma unroll
            for (int s = 0; s < 6; ++s) {
                const int row = rows6[s];
                float4 wv = *(const float4*)&Wbuf[row][WSWZ(row, kb * 4)];
                acc[s]     = fmaf(xa.x, wv.x, acc[s]);
                acc[s]     = fmaf(xa.y, wv.y, acc[s]);
                acc[s]     = fmaf(xa.z, wv.z, acc[s]);
                acc[s]     = fmaf(xa.w, wv.w, acc[s]);
                acc[6 + s] = fmaf(xb.x, wv.x, acc[6 + s]);
                acc[6 + s] = fmaf(xb.y, wv.y, acc[6 + s]);
                acc[6 + s] = fmaf(xb.z, wv.z, acc[6 + s]);
                acc[6 + s] = fmaf(xb.w, wv.w, acc[6 + s]);
            }
        }
    }

    const float bi0 = b_ih[j]      + b_hh[j];
    const float bi1 = b_ih[17 + j] + b_hh[17 + j];
    const float bi2 = b_ih[34 + j] + b_hh[34 + j];
    const float bi3 = b_ih[51 + j] + b_hh[51 + j];
    const float xgAi = acc[0] + bi0, xgAf = acc[1] + bi1;
    const float xgAg = acc[2] + bi2, xgAo = acc[3] + bi3;
    const float xgBi = acc[6] + bi0, xgBf = acc[7] + bi1;
    const float xgBg = acc[8] + bi2, xgBo = acc[9] + bi3;
    float hA = acc[4]  + b_h0[j], cA = acc[5]  + b_c0[j];
    float hB = acc[10] + b_h0[j], cB = acc[11] + b_c0[j];

    // ---- W_hh rows for gates i,f,g,o of element j -> packed register pairs ----
    float2v Wip[8], Wfp[8], Wgp[8], Wop[8];
    float   Wi16, Wf16, Wg16, Wo16;
#pragma unroll
    for (int p = 0; p < 8; ++p) {
        Wip[p] = float2v{ Wl[(0 * H + j) * H + 2 * p], Wl[(0 * H + j) * H + 2 * p + 1] };
        Wfp[p] = float2v{ Wl[(1 * H + j) * H + 2 * p], Wl[(1 * H + j) * H + 2 * p + 1] };
        Wgp[p] = float2v{ Wl[(2 * H + j) * H + 2 * p], Wl[(2 * H + j) * H + 2 * p + 1] };
        Wop[p] = float2v{ Wl[(3 * H + j) * H + 2 * p], Wl[(3 * H + j) * H + 2 * p + 1] };
        asm volatile("" : "+v"(Wip[p]), "+v"(Wfp[p]), "+v"(Wgp[p]), "+v"(Wop[p]));
    }
    Wi16 = Wl[(0 * H + j) * H + 16];
    Wf16 = Wl[(1 * H + j) * H + 16];
    Wg16 = Wl[(2 * H + j) * H + 16];
    Wo16 = Wl[(3 * H + j) * H + 16];
    asm volatile("" : "+v"(Wi16), "+v"(Wf16), "+v"(Wg16), "+v"(Wo16));

    // ---- phase 2: R13 depth-2 A/B pipeline, zero barriers, packed dots ----
    float* orowA = out + (size_t)growA * (TSTEPS * H) + j;
    float* orowB = out + (size_t)growB * (TSTEPS * H) + j;
    const float* hbA = &hbuf[w][rl][0];
    const float* hbB = &hbuf[w][3 + rl][0];

    // prologue: A's step-0 exchange
    if (active) hbuf[w][rl][j] = hA;
    float4 a0 = *(const float4*)&hbA[0];
    float4 a1 = *(const float4*)&hbA[4];
    float4 a2 = *(const float4*)&hbA[8];
    float4 a3 = *(const float4*)&hbA[12];
    float  a4 = hbA[16];

    for (int tt = 0; tt < TSTEPS; ++tt) {
        // --- B exchange for this step (consumed after A's compute) ---
        if (active) hbuf[w][3 + rl][j] = hB;
        float4 b0 = *(const float4*)&hbB[0];
        float4 b1 = *(const float4*)&hbB[4];
        float4 b2 = *(const float4*)&hbB[8];
        float4 b3 = *(const float4*)&hbB[12];
        float  b4 = hbB[16];

        // --- A compute (packed dot: 8 pk_fma per gate + k16 scalar) ---
        {
            float2v hp[8] = { float2v{a0.x, a0.y}, float2v{a0.z, a0.w},
                              float2v{a1.x, a1.y}, float2v{a1.z, a1.w},
                              float2v{a2.x, a2.y}, float2v{a2.z, a2.w},
                              float2v{a3.x, a3.y}, float2v{a3.z, a3.w} };
            float2v vi = float2v{xgAi, 0.0f}, vf = float2v{xgAf, 0.0f};
            float2v vg = float2v{xgAg, 0.0f}, vo = float2v{xgAo, 0.0f};
#pragma unroll
            for (int p = 0; p < 8; ++p) {
                PKFMA(vi, Wip[p], hp[p]);
                PKFMA(vf, Wfp[p], hp[p]);
                PKFMA(vg, Wgp[p], hp[p]);
                PKFMA(vo, Wop[p], hp[p]);
            }
            float ai = vi.x + vi.y; ai = fmaf(Wi16, a4, ai);
            float af = vf.x + vf.y; af = fmaf(Wf16, a4, af);
            float ag = vg.x + vg.y; ag = fmaf(Wg16, a4, ag);
            float ao = vo.x + vo.y; ao = fmaf(Wo16, a4, ao);
            const float ig = fsigmoid(ai), fg = fsigmoid(af);
            const float gv = ftanhf(ag),  og = fsigmoid(ao);
            cA = fmaf(fg, cA, ig * gv);
            hA = og * ftanhf(cA);
        }

        // --- A exchange for NEXT step (hidden under B's compute) ---
        if (active) hbuf[w][rl][j] = hA;
        a0 = *(const float4*)&hbA[0];
        a1 = *(const float4*)&hbA[4];
        a2 = *(const float4*)&hbA[8];
        a3 = *(const float4*)&hbA[12];
        a4 = hbA[16];

        // --- B compute ---
        {
            float2v hp[8] = { float2v{b0.x, b0.y}, float2v{b0.z, b0.w},
                              float2v{b1.x, b1.y}, float2v{b1.z, b1.w},
                              float2v{b2.x, b2.y}, float2v{b2.z, b2.w},
                              float2v{b3.x, b3.y}, float2v{b3.z, b3.w} };
            float2v vi = float2v{xgBi, 0.0f}, vf = float2v{xgBf, 0.0f};
            float2v vg = float2v{xgBg, 0.0f}, vo = float2v{xgBo, 0.0f};
#pragma unroll
            for (int p = 0; p < 8; ++p) {
                PKFMA(vi, Wip[p], hp[p]);
                PKFMA(vf, Wfp[p], hp[p]);
                PKFMA(vg, Wgp[p], hp[p]);
                PKFMA(vo, Wop[p], hp[p]);
            }
            float ai = vi.x + vi.y; ai = fmaf(Wi16, b4, ai);
            float af = vf.x + vf.y; af = fmaf(Wf16, b4, af);
            float ag = vg.x + vg.y; ag = fmaf(Wg16, b4, ag);
            float ao = vo.x + vo.y; ao = fmaf(Wo16, b4, ao);
            const float ig = fsigmoid(ai), fg = fsigmoid(af);
            const float gv = ftanhf(ag),  og = fsigmoid(ao);
            cB = fmaf(fg, cB, ig * gv);
            hB = og * ftanhf(cB);
        }

        // --- stores (async vmem, off the critical path) ---
        if (validA) orowA[tt * H] = hA;
        if (validB) orowB[tt * H] = hB;
    }
}

extern "C" void kernel_launch(void* const* d_in, const int* in_sizes, int n_in,
                              void* d_out, int out_size, void* d_ws, size_t ws_size,
                              hipStream_t stream)
{
    const float* x    = (const float*)d_in[0];
    const float* W_h0 = (const float*)d_in[1];
    const float* b_h0 = (const float*)d_in[2];
    const float* W_c0 = (const float*)d_in[3];
    const float* b_c0 = (const float*)d_in[4];
    const float* W_ih = (const float*)d_in[5];
    const float* W_hh = (const float*)d_in[6];
    const float* b_ih = (const float*)d_in[7];
    const float* b_hh = (const float*)d_in[8];
    float* out = (float*)d_out;

    (void)d_ws; (void)ws_size;  // no workspace used

    const int nblk = (BTOT + RPB - 1) / RPB;   // 683
    hipLaunchKernelGGL(lstm_fused, dim3(nblk), dim3(TPB), 0, stream,
                       x, W_h0, b_h0, W_c0, b_c0, W_ih, W_hh, b_ih, b_hh, out);
}